// Round 5
// baseline (606.627 us; speedup 1.0000x reference)
//
#include <hip/hip_runtime.h>
#include <math.h>

typedef unsigned short u16;
typedef short bf16x8 __attribute__((ext_vector_type(8)));
typedef float f32x4 __attribute__((ext_vector_type(4)));

// Problem constants (B=2, S=4096, H=2048, NH=16, NKV=4, HD=128, g=1024)

__device__ __forceinline__ u16 f2bf(float x) {
  union { float f; unsigned u; } c; c.f = x;
  unsigned r = (c.u + 0x7FFFu + ((c.u >> 16) & 1u)) >> 16;  // RNE
  return (u16)r;
}
__device__ __forceinline__ float bf2f(u16 x) {
  union { unsigned u; float f; } c; c.u = ((unsigned)x) << 16;
  return c.f;
}

// async 16B global -> LDS (wave-uniform LDS base + lane*16)
#define GLD16(gp, lp)                                                   \
  __builtin_amdgcn_global_load_lds(                                     \
      (__attribute__((address_space(1))) void*)(gp),                    \
      (__attribute__((address_space(3))) void*)(lp), 16, 0, 0)

// ---------------------------------------------------------------------------
// fp32 -> bf16 elementwise cast (hidden_states)
// ---------------------------------------------------------------------------
__global__ __launch_bounds__(256) void cast_bf16_vec(
    const float* __restrict__ X, u16* __restrict__ Y) {
  const size_t i = ((size_t)blockIdx.x * 256 + threadIdx.x) * 4;
  float4 v = *(const float4*)(X + i);
  ushort4 o;
  o.x = f2bf(v.x); o.y = f2bf(v.y); o.z = f2bf(v.z); o.w = f2bf(v.w);
  *(ushort4*)(Y + i) = o;
}

// ---------------------------------------------------------------------------
// W (K x N fp32, row-major) -> Wt (N x K bf16, row-major). 64x64 LDS tiles.
// ---------------------------------------------------------------------------
__global__ __launch_bounds__(256) void wt_cast(
    const float* __restrict__ W, u16* __restrict__ Wt, int K, int N) {
  const int bk = blockIdx.y * 64;
  const int bn = blockIdx.x * 64;
  __shared__ float T[64 * 65];
  const int tid = threadIdx.x;
  #pragma unroll
  for (int u = 0; u < 16; ++u) {
    int idx = tid + u * 256;
    int kl = idx >> 6, nl = idx & 63;
    T[kl * 65 + nl] = W[(size_t)(bk + kl) * N + bn + nl];
  }
  __syncthreads();
  #pragma unroll
  for (int u = 0; u < 16; ++u) {
    int idx = tid + u * 256;
    int nl = idx >> 6, kl = idx & 63;
    Wt[(size_t)(bn + nl) * K + bk + kl] = f2bf(T[kl * 65 + nl]);
  }
}

// ---------------------------------------------------------------------------
// bf16 MFMA GEMM (m97 structure): C[M,N] = A[M,K] @ Bt[N,K]^T
// 128x128 tile, BK=32, 256 thr / 4 waves, each wave 64x64 via 4x4 16x16x32.
// ---------------------------------------------------------------------------
__global__ __launch_bounds__(256) void gemm_bf16(
    const u16* __restrict__ A, const u16* __restrict__ Bt,
    float* __restrict__ Cf, u16* __restrict__ Cb, int M, int N, int K) {
  __shared__ u16 As[128 * 32];
  __shared__ u16 Bs[128 * 32];

  const int tid = threadIdx.x;
  const int bm = blockIdx.y * 128;
  const int bn = blockIdx.x * 128;
  const int w = tid >> 6, lane = tid & 63;
  const int col = lane & 15, quad = lane >> 4;
  const int mblk = (w & 1) * 64, nblk = (w >> 1) * 64;

  const int srow = tid >> 2;          // 0..63
  const int sseg = (tid & 3) * 8;     // 8 bf16 = 16 B

  const u16* ag0 = A + (size_t)(bm + srow) * K + sseg;
  const u16* ag1 = A + (size_t)(bm + 64 + srow) * K + sseg;
  const u16* bg0 = Bt + (size_t)(bn + srow) * K + sseg;
  const u16* bg1 = Bt + (size_t)(bn + 64 + srow) * K + sseg;
  u16* al = &As[srow * 32 + sseg];
  u16* bl = &Bs[srow * 32 + sseg];

  f32x4 acc[4][4];
  #pragma unroll
  for (int i = 0; i < 4; ++i)
    #pragma unroll
    for (int j = 0; j < 4; ++j) acc[i][j] = (f32x4)(0.0f);

  for (int k0 = 0; k0 < K; k0 += 32) {
    __syncthreads();
    GLD16(ag0 + k0, al);
    GLD16(ag1 + k0, al + 64 * 32);
    GLD16(bg0 + k0, bl);
    GLD16(bg1 + k0, bl + 64 * 32);
    __syncthreads();

    bf16x8 af[4], bfr[4];
    #pragma unroll
    for (int i = 0; i < 4; ++i)
      af[i] = *(const bf16x8*)&As[(mblk + 16 * i + col) * 32 + quad * 8];
    #pragma unroll
    for (int j = 0; j < 4; ++j)
      bfr[j] = *(const bf16x8*)&Bs[(nblk + 16 * j + col) * 32 + quad * 8];
    #pragma unroll
    for (int i = 0; i < 4; ++i)
      #pragma unroll
      for (int j = 0; j < 4; ++j)
        acc[i][j] = __builtin_amdgcn_mfma_f32_16x16x32_bf16(af[i], bfr[j], acc[i][j], 0, 0, 0);
  }

  // C/D layout: col = lane&15, row = quad*4 + reg  [verified m89/m91]
  #pragma unroll
  for (int i = 0; i < 4; ++i) {
    const int row0 = bm + mblk + 16 * i + quad * 4;
    #pragma unroll
    for (int j = 0; j < 4; ++j) {
      const int cc = bn + nblk + 16 * j + col;
      #pragma unroll
      for (int r = 0; r < 4; ++r) {
        if (Cb) Cb[(size_t)(row0 + r) * N + cc] = f2bf(acc[i][j][r]);
        else    Cf[(size_t)(row0 + r) * N + cc] = acc[i][j][r];
      }
    }
  }
}

// ---------------------------------------------------------------------------
// Fused RoPE on the QKV buffer (8192 rows x 3072 cols bf16).
// head 0..15 = Q (1/sqrt(128) folded in), 16..19 = K.
// ---------------------------------------------------------------------------
__global__ __launch_bounds__(256) void rope_qkv(
    u16* __restrict__ QKV, const int* __restrict__ pos) {
  const unsigned idx = blockIdx.x * 256 + threadIdx.x;
  const int d = idx & 63;
  const unsigned rest = idx >> 6;
  const int hh = rest % 20;
  const unsigned bs = rest / 20;

  const int colbase = (hh < 16) ? hh * 128 : 2048 + (hh - 16) * 128;
  u16* p = QKV + (size_t)bs * 3072 + colbase + d;
  const float x0 = bf2f(p[0]);
  const float x1 = bf2f(p[64]);
  const float t = (float)pos[bs];
  const float inv_freq = __expf((float)d * -0.14391156509676332f);  // ln(1e4)/64
  float s, c;
  __sincosf(t * inv_freq, &s, &c);
  const float sc = (hh < 16) ? 0.08838834764831845f : 1.0f;  // 1/sqrt(128) into Q
  p[0]  = f2bf((x0 * c - x1 * s) * sc);
  p[64] = f2bf((x1 * c + x0 * s) * sc);
}

// ---------------------------------------------------------------------------
// V columns of QKV (offset 2560, stride 3072) -> Vt (B, NKV, 128, S)
// ---------------------------------------------------------------------------
__global__ __launch_bounds__(256) void v_transpose(
    const u16* __restrict__ QKV, u16* __restrict__ Vt) {
  const int bid = blockIdx.x;
  const int st = bid & 63;
  const int kvh = (bid >> 6) & 3;
  const int b = bid >> 8;
  __shared__ u16 T[64 * 136];
  const int tid = threadIdx.x;
  #pragma unroll
  for (int u = 0; u < 4; ++u) {
    int idx = tid + u * 256;
    int sl = idx >> 4, ch = idx & 15;
    *(uint4*)&T[sl * 136 + ch * 8] =
        *(const uint4*)(QKV + ((size_t)(b * 4096 + st * 64 + sl)) * 3072 + 2560 + kvh * 128 + ch * 8);
  }
  __syncthreads();
  #pragma unroll
  for (int u = 0; u < 32; ++u) {
    int idx = tid + u * 256;
    int d = idx >> 6, sl = idx & 63;
    Vt[((size_t)((b * 4 + kvh) * 128 + d)) * 4096 + st * 64 + sl] = T[sl * 136 + d];
  }
}

// ---------------------------------------------------------------------------
// MFMA flash attention, max-free softmax, S2-shift indexing.
// Block = 512 thr / 8 waves; 128-query tile of one (b,group,head); 64-key
// tiles with register-prefetch double buffering. Wave w owns q-rows w*16..+15.
// Q pre-scaled by 1/sqrt(128); Q frags loaded straight from global.
// LDS 54.3 KB -> 2 blocks/CU.
// ---------------------------------------------------------------------------
__global__ __launch_bounds__(512, 4) void attn_mfma(
    const u16* __restrict__ QKV, const u16* __restrict__ Vt,
    u16* __restrict__ Ob) {
  __shared__ u16 Ks[64 * 136];    // [key][128d]
  __shared__ u16 Vs[128 * 72];    // [dim][64key]
  __shared__ u16 Ps[8][16 * 72];  // per-wave P [16q][64key]

  const int bid = blockIdx.x;
  const int qt = 7 - (bid & 7);             // heavy tiles first
  const int h  = (bid >> 3) & 15;
  const int gi = (bid >> 7) & 3;
  const int b  = bid >> 9;

  const int tid = threadIdx.x;
  const int w = tid >> 6, lane = tid & 63;
  const int col = lane & 15, quad = lane >> 4;

  const int shift = (h >= 8) ? 512 : 0;
  const int base_s = gi * 1024;
  const int kvh = h >> 2;
  const int ktmax = 2 * qt + 1;

  // staging index split (512 threads)
  const int krow = tid >> 4, kch = tid & 15;   // K: 2 chunks: rows krow, 32+krow
  const int vrow = tid >> 3, vch = tid & 7;    // V: 2 chunks: rows vrow, 64+vrow

  const u16* ksrc = QKV + ((size_t)(b * 4096)) * 3072 + 2048 + kvh * 128;
  const u16* vsrc = Vt + ((size_t)((b * 4 + kvh) * 128)) * 4096;

  // ---- prefetch K/V tile 0 into regs ----
  uint4 kreg[2], vreg[2];
  {
    const int sk0 = (base_s + shift) & 4095;
    kreg[0] = *(const uint4*)(ksrc + (size_t)(sk0 + krow) * 3072 + kch * 8);
    kreg[1] = *(const uint4*)(ksrc + (size_t)(sk0 + 32 + krow) * 3072 + kch * 8);
    vreg[0] = *(const uint4*)(vsrc + (size_t)vrow * 4096 + sk0 + vch * 8);
    vreg[1] = *(const uint4*)(vsrc + (size_t)(64 + vrow) * 4096 + sk0 + vch * 8);
  }

  // ---- Q A-frags straight from global (per-lane rows, 16B segments) ----
  bf16x8 aq[4];
  {
    const int qg = qt * 128 + w * 16 + col;
    const int sqr = (base_s + qg + shift) & 4095;
    const u16* qp = QKV + ((size_t)(b * 4096 + sqr)) * 3072 + h * 128;
    #pragma unroll
    for (int kk = 0; kk < 4; ++kk)
      aq[kk] = *(const bf16x8*)(qp + kk * 32 + quad * 8);
  }

  f32x4 o[8];
  #pragma unroll
  for (int jd = 0; jd < 8; ++jd) o[jd] = (f32x4)(0.0f);
  float lp[4] = {0.0f, 0.0f, 0.0f, 0.0f};

  u16* Pw = &Ps[w][0];
  const int qrow_l = qt * 128 + w * 16 + quad * 4;  // + r (group-local q row)

  for (int kt = 0; kt <= ktmax; ++kt) {
    __syncthreads();  // all waves done reading Ks/Vs of tile kt-1
    // regs -> LDS
    *(uint4*)&Ks[krow * 136 + kch * 8] = kreg[0];
    *(uint4*)&Ks[(32 + krow) * 136 + kch * 8] = kreg[1];
    *(uint4*)&Vs[vrow * 72 + vch * 8] = vreg[0];
    *(uint4*)&Vs[(64 + vrow) * 72 + vch * 8] = vreg[1];
    __syncthreads();

    // issue prefetch of tile kt+1 (overlaps all compute below)
    if (kt < ktmax) {
      const int skn = (base_s + (kt + 1) * 64 + shift) & 4095;
      kreg[0] = *(const uint4*)(ksrc + (size_t)(skn + krow) * 3072 + kch * 8);
      kreg[1] = *(const uint4*)(ksrc + (size_t)(skn + 32 + krow) * 3072 + kch * 8);
      vreg[0] = *(const uint4*)(vsrc + (size_t)vrow * 4096 + skn + vch * 8);
      vreg[1] = *(const uint4*)(vsrc + (size_t)(64 + vrow) * 4096 + skn + vch * 8);
    }

    // ---- S = Q K^T : 16 MFMA ----
    f32x4 sc[4];
    #pragma unroll
    for (int j = 0; j < 4; ++j) sc[j] = (f32x4)(0.0f);
    #pragma unroll
    for (int kk = 0; kk < 4; ++kk) {
      #pragma unroll
      for (int j = 0; j < 4; ++j) {
        bf16x8 bk = *(const bf16x8*)&Ks[(16 * j + col) * 136 + kk * 32 + quad * 8];
        sc[j] = __builtin_amdgcn_mfma_f32_16x16x32_bf16(aq[kk], bk, sc[j], 0, 0, 0);
      }
    }

    // ---- exp (max-free), mask on last two tiles, P write, l accum ----
    if (kt >= 2 * qt) {
      #pragma unroll
      for (int j = 0; j < 4; ++j) {
        #pragma unroll
        for (int r = 0; r < 4; ++r) {
          float p = __expf(sc[j][r]);
          if ((kt * 64 + 16 * j + col) > (qrow_l + r)) p = 0.0f;
          lp[r] += p;
          Pw[(quad * 4 + r) * 72 + 16 * j + col] = f2bf(p);
        }
      }
    } else {
      #pragma unroll
      for (int j = 0; j < 4; ++j) {
        #pragma unroll
        for (int r = 0; r < 4; ++r) {
          float p = __expf(sc[j][r]);
          lp[r] += p;
          Pw[(quad * 4 + r) * 72 + 16 * j + col] = f2bf(p);
        }
      }
    }
    // Ps is wave-private: in-wave ds ordering handles write->read

    // ---- O += P V : 16 MFMA ----
    #pragma unroll
    for (int ks = 0; ks < 2; ++ks) {
      bf16x8 ap = *(const bf16x8*)&Pw[col * 72 + ks * 32 + quad * 8];
      #pragma unroll
      for (int jd = 0; jd < 8; ++jd) {
        bf16x8 bv = *(const bf16x8*)&Vs[(16 * jd + col) * 72 + ks * 32 + quad * 8];
        o[jd] = __builtin_amdgcn_mfma_f32_16x16x32_bf16(ap, bv, o[jd], 0, 0, 0);
      }
    }
  }

  // ---- reduce denominators across the 16 col-lanes ----
  #pragma unroll
  for (int r = 0; r < 4; ++r) {
    lp[r] += __shfl_xor(lp[r], 1, 64);
    lp[r] += __shfl_xor(lp[r], 2, 64);
    lp[r] += __shfl_xor(lp[r], 4, 64);
    lp[r] += __shfl_xor(lp[r], 8, 64);
  }

  // ---- normalize + store (output lands at shifted seq pos = un-shift) ----
  #pragma unroll
  for (int r = 0; r < 4; ++r) {
    const int qg = qt * 128 + w * 16 + quad * 4 + r;
    const int sq = (base_s + qg + shift) & 4095;
    u16* dst = Ob + ((size_t)(b * 4096 + sq)) * 2048 + h * 128;
    const float inv = 1.0f / lp[r];
    #pragma unroll
    for (int jd = 0; jd < 8; ++jd)
      dst[16 * jd + col] = f2bf(o[jd][r] * inv);
  }
}

// ---------------------------------------------------------------------------
extern "C" void kernel_launch(void* const* d_in, const int* in_sizes, int n_in,
                              void* d_out, int out_size, void* d_ws, size_t ws_size,
                              hipStream_t stream) {
  const float* hs = (const float*)d_in[0];
  const int*   pos = (const int*)d_in[2];
  const float* Wq = (const float*)d_in[3];
  const float* Wk = (const float*)d_in[4];
  const float* Wv = (const float*)d_in[5];
  const float* Wo = (const float*)d_in[6];

  char* ws = (char*)d_ws;
  u16* hsb   = (u16*)ws; ws += (size_t)8192 * 2048 * 2;
  u16* Wqkvt = (u16*)ws; ws += (size_t)3072 * 2048 * 2;
  u16* Wot   = (u16*)ws; ws += (size_t)2048 * 2048 * 2;
  u16* QKVb  = (u16*)ws; ws += (size_t)8192 * 3072 * 2;
  u16* Vtt   = (u16*)ws; ws += (size_t)2 * 4 * 128 * 4096 * 2;
  u16* Obh   = (u16*)ws; ws += (size_t)8192 * 2048 * 2;

  dim3 blk(256);

  cast_bf16_vec<<<16384, blk, 0, stream>>>(hs, hsb);
  // Wqkvt rows: 0..2047 = Wq^T, 2048..2559 = Wk^T, 2560..3071 = Wv^T
  wt_cast<<<dim3(32, 32), blk, 0, stream>>>(Wq, Wqkvt, 2048, 2048);
  wt_cast<<<dim3(8, 32),  blk, 0, stream>>>(Wk, Wqkvt + (size_t)2048 * 2048, 2048, 512);
  wt_cast<<<dim3(8, 32),  blk, 0, stream>>>(Wv, Wqkvt + (size_t)2560 * 2048, 2048, 512);
  wt_cast<<<dim3(32, 32), blk, 0, stream>>>(Wo, Wot, 2048, 2048);

  // Fused QKV projection: (8192 x 2048) @ (3072 x 2048)^T -> 8192 x 3072 bf16
  gemm_bf16<<<dim3(24, 64), blk, 0, stream>>>(hsb, Wqkvt, nullptr, QKVb, 8192, 3072, 2048);

  rope_qkv<<<40960, blk, 0, stream>>>(QKVb, pos);
  v_transpose<<<512, blk, 0, stream>>>(QKVb, Vtt);

  // flash attention: 1024 blocks x 512 threads
  attn_mfma<<<1024, dim3(512), 0, stream>>>(QKVb, Vtt, Obh);

  gemm_bf16<<<dim3(16, 64), blk, 0, stream>>>(Obh, Wot, (float*)d_out, nullptr, 8192, 2048, 2048);
}

// Round 6
// 592.192 us; speedup vs baseline: 1.0244x; 1.0244x over previous
//
#include <hip/hip_runtime.h>
#include <math.h>

typedef unsigned short u16;
typedef short bf16x8 __attribute__((ext_vector_type(8)));
typedef float f32x4 __attribute__((ext_vector_type(4)));

// Problem constants (B=2, S=4096, H=2048, NH=16, NKV=4, HD=128, g=1024)

__device__ __forceinline__ u16 f2bf(float x) {
  union { float f; unsigned u; } c; c.f = x;
  unsigned r = (c.u + 0x7FFFu + ((c.u >> 16) & 1u)) >> 16;  // RNE
  return (u16)r;
}
__device__ __forceinline__ float bf2f(u16 x) {
  union { unsigned u; float f; } c; c.u = ((unsigned)x) << 16;
  return c.f;
}

// async 16B global -> LDS (wave-uniform LDS base + lane*16)
#define GLD16(gp, lp)                                                   \
  __builtin_amdgcn_global_load_lds(                                     \
      (__attribute__((address_space(1))) void*)(gp),                    \
      (__attribute__((address_space(3))) void*)(lp), 16, 0, 0)

// ---------------------------------------------------------------------------
// fp32 -> bf16 elementwise cast (hidden_states)
// ---------------------------------------------------------------------------
__global__ __launch_bounds__(256) void cast_bf16_vec(
    const float* __restrict__ X, u16* __restrict__ Y) {
  const size_t i = ((size_t)blockIdx.x * 256 + threadIdx.x) * 4;
  float4 v = *(const float4*)(X + i);
  ushort4 o;
  o.x = f2bf(v.x); o.y = f2bf(v.y); o.z = f2bf(v.z); o.w = f2bf(v.w);
  *(ushort4*)(Y + i) = o;
}

// ---------------------------------------------------------------------------
// W (K x N fp32, row-major) -> Wt (N x K bf16, row-major). 64x64 LDS tiles.
// ---------------------------------------------------------------------------
__global__ __launch_bounds__(256) void wt_cast(
    const float* __restrict__ W, u16* __restrict__ Wt, int K, int N) {
  const int bk = blockIdx.y * 64;
  const int bn = blockIdx.x * 64;
  __shared__ float T[64 * 65];
  const int tid = threadIdx.x;
  #pragma unroll
  for (int u = 0; u < 16; ++u) {
    int idx = tid + u * 256;
    int kl = idx >> 6, nl = idx & 63;
    T[kl * 65 + nl] = W[(size_t)(bk + kl) * N + bn + nl];
  }
  __syncthreads();
  #pragma unroll
  for (int u = 0; u < 16; ++u) {
    int idx = tid + u * 256;
    int nl = idx >> 6, kl = idx & 63;
    Wt[(size_t)(bn + nl) * K + bk + kl] = f2bf(T[kl * 65 + nl]);
  }
}

// ---------------------------------------------------------------------------
// bf16 MFMA GEMM (m97 structure): C[M,N] = A[M,K] @ Bt[N,K]^T
// 128x128 tile, BK=32, 256 thr / 4 waves, each wave 64x64 via 4x4 16x16x32.
// ---------------------------------------------------------------------------
__global__ __launch_bounds__(256) void gemm_bf16(
    const u16* __restrict__ A, const u16* __restrict__ Bt,
    float* __restrict__ Cf, u16* __restrict__ Cb, int M, int N, int K) {
  __shared__ u16 As[128 * 32];
  __shared__ u16 Bs[128 * 32];

  const int tid = threadIdx.x;
  const int bm = blockIdx.y * 128;
  const int bn = blockIdx.x * 128;
  const int w = tid >> 6, lane = tid & 63;
  const int col = lane & 15, quad = lane >> 4;
  const int mblk = (w & 1) * 64, nblk = (w >> 1) * 64;

  const int srow = tid >> 2;          // 0..63
  const int sseg = (tid & 3) * 8;     // 8 bf16 = 16 B

  const u16* ag0 = A + (size_t)(bm + srow) * K + sseg;
  const u16* ag1 = A + (size_t)(bm + 64 + srow) * K + sseg;
  const u16* bg0 = Bt + (size_t)(bn + srow) * K + sseg;
  const u16* bg1 = Bt + (size_t)(bn + 64 + srow) * K + sseg;
  u16* al = &As[srow * 32 + sseg];
  u16* bl = &Bs[srow * 32 + sseg];

  f32x4 acc[4][4];
  #pragma unroll
  for (int i = 0; i < 4; ++i)
    #pragma unroll
    for (int j = 0; j < 4; ++j) acc[i][j] = (f32x4)(0.0f);

  for (int k0 = 0; k0 < K; k0 += 32) {
    __syncthreads();
    GLD16(ag0 + k0, al);
    GLD16(ag1 + k0, al + 64 * 32);
    GLD16(bg0 + k0, bl);
    GLD16(bg1 + k0, bl + 64 * 32);
    __syncthreads();

    bf16x8 af[4], bfr[4];
    #pragma unroll
    for (int i = 0; i < 4; ++i)
      af[i] = *(const bf16x8*)&As[(mblk + 16 * i + col) * 32 + quad * 8];
    #pragma unroll
    for (int j = 0; j < 4; ++j)
      bfr[j] = *(const bf16x8*)&Bs[(nblk + 16 * j + col) * 32 + quad * 8];
    #pragma unroll
    for (int i = 0; i < 4; ++i)
      #pragma unroll
      for (int j = 0; j < 4; ++j)
        acc[i][j] = __builtin_amdgcn_mfma_f32_16x16x32_bf16(af[i], bfr[j], acc[i][j], 0, 0, 0);
  }

  // C/D layout: col = lane&15, row = quad*4 + reg  [verified m89/m91]
  #pragma unroll
  for (int i = 0; i < 4; ++i) {
    const int row0 = bm + mblk + 16 * i + quad * 4;
    #pragma unroll
    for (int j = 0; j < 4; ++j) {
      const int cc = bn + nblk + 16 * j + col;
      #pragma unroll
      for (int r = 0; r < 4; ++r) {
        if (Cb) Cb[(size_t)(row0 + r) * N + cc] = f2bf(acc[i][j][r]);
        else    Cf[(size_t)(row0 + r) * N + cc] = acc[i][j][r];
      }
    }
  }
}

// ---------------------------------------------------------------------------
// Fused RoPE on the QKV buffer (8192 rows x 3072 cols bf16).
// head 0..15 = Q (1/sqrt(128) folded in), 16..19 = K.
// ---------------------------------------------------------------------------
__global__ __launch_bounds__(256) void rope_qkv(
    u16* __restrict__ QKV, const int* __restrict__ pos) {
  const unsigned idx = blockIdx.x * 256 + threadIdx.x;
  const int d = idx & 63;
  const unsigned rest = idx >> 6;
  const int hh = rest % 20;
  const unsigned bs = rest / 20;

  const int colbase = (hh < 16) ? hh * 128 : 2048 + (hh - 16) * 128;
  u16* p = QKV + (size_t)bs * 3072 + colbase + d;
  const float x0 = bf2f(p[0]);
  const float x1 = bf2f(p[64]);
  const float t = (float)pos[bs];
  const float inv_freq = __expf((float)d * -0.14391156509676332f);  // ln(1e4)/64
  float s, c;
  __sincosf(t * inv_freq, &s, &c);
  const float sc = (hh < 16) ? 0.08838834764831845f : 1.0f;  // 1/sqrt(128) into Q
  p[0]  = f2bf((x0 * c - x1 * s) * sc);
  p[64] = f2bf((x1 * c + x0 * s) * sc);
}

// ---------------------------------------------------------------------------
// V columns of QKV (offset 2560, stride 3072) -> Vt (B, NKV, 128, S)
// ---------------------------------------------------------------------------
__global__ __launch_bounds__(256) void v_transpose(
    const u16* __restrict__ QKV, u16* __restrict__ Vt) {
  const int bid = blockIdx.x;
  const int st = bid & 63;
  const int kvh = (bid >> 6) & 3;
  const int b = bid >> 8;
  __shared__ u16 T[64 * 136];
  const int tid = threadIdx.x;
  #pragma unroll
  for (int u = 0; u < 4; ++u) {
    int idx = tid + u * 256;
    int sl = idx >> 4, ch = idx & 15;
    *(uint4*)&T[sl * 136 + ch * 8] =
        *(const uint4*)(QKV + ((size_t)(b * 4096 + st * 64 + sl)) * 3072 + 2560 + kvh * 128 + ch * 8);
  }
  __syncthreads();
  #pragma unroll
  for (int u = 0; u < 32; ++u) {
    int idx = tid + u * 256;
    int d = idx >> 6, sl = idx & 63;
    Vt[((size_t)((b * 4 + kvh) * 128 + d)) * 4096 + st * 64 + sl] = T[sl * 136 + d];
  }
}

// ---------------------------------------------------------------------------
// MFMA flash attention, max-free softmax, S2-shift indexing.
// Block = 512 thr / 8 waves; 128-query tile of one (b,group,head); 64-key
// tiles. Wave w owns q-rows w*16..+15. Q pre-scaled by 1/sqrt(128).
// QK^T computed SWAPPED (St = K * Q^T) so the C-frag has col=q, row=key:
//   - P writes to [q][key] LDS pack into 4x b64 stores
//   - softmax denominator is one scalar per lane (2 shuffles at the end)
// K/V global loads issued BEFORE the barrier (latency overlaps barrier wait);
// regs die right after the LDS store -> peak VGPR ~75, no spill at LB(512,6).
// LDS 54272 B -> 3 blocks/CU at <=85 VGPRs.
// ---------------------------------------------------------------------------
__global__ __launch_bounds__(512, 6) void attn_mfma(
    const u16* __restrict__ QKV, const u16* __restrict__ Vt,
    u16* __restrict__ Ob) {
  __shared__ u16 Ks[64 * 136];    // [key][128d]
  __shared__ u16 Vs[128 * 72];    // [dim][64key]
  __shared__ u16 Ps[8][16 * 72];  // per-wave P [16q][64key]

  const int bid = blockIdx.x;
  const int qt = 7 - (bid & 7);             // heavy tiles first
  const int h  = (bid >> 3) & 15;
  const int gi = (bid >> 7) & 3;
  const int b  = bid >> 9;

  const int tid = threadIdx.x;
  const int w = tid >> 6, lane = tid & 63;
  const int col = lane & 15, quad = lane >> 4;

  const int shift = (h >= 8) ? 512 : 0;
  const int base_s = gi * 1024;
  const int kvh = h >> 2;
  const int ktmax = 2 * qt + 1;

  // staging index split (512 threads)
  const int krow = tid >> 4, kch = tid & 15;   // K: rows krow, 32+krow
  const int vrow = tid >> 3, vch = tid & 7;    // V: rows vrow, 64+vrow

  const u16* ksrc = QKV + ((size_t)(b * 4096)) * 3072 + 2048 + kvh * 128;
  const u16* vsrc = Vt + ((size_t)((b * 4 + kvh) * 128)) * 4096;

  // ---- Q B-frags straight from global (per-lane rows, 16B segments) ----
  bf16x8 aq[4];
  {
    const int qg = qt * 128 + w * 16 + col;
    const int sqr = (base_s + qg + shift) & 4095;
    const u16* qp = QKV + ((size_t)(b * 4096 + sqr)) * 3072 + h * 128;
    #pragma unroll
    for (int kk = 0; kk < 4; ++kk)
      aq[kk] = *(const bf16x8*)(qp + kk * 32 + quad * 8);
  }

  f32x4 o[8];
  #pragma unroll
  for (int jd = 0; jd < 8; ++jd) o[jd] = (f32x4)(0.0f);
  float lsum = 0.0f;  // denominator partial for q = col (this lane's column)

  u16* Pw = &Ps[w][0];
  const int qrow = qt * 128 + w * 16 + col;  // q row this lane's S-col holds

  for (int kt = 0; kt <= ktmax; ++kt) {
    const int sk0 = (base_s + kt * 64 + shift) & 4095;  // tile never crosses wrap

    // issue global loads BEFORE the barrier: latency overlaps barrier wait
    uint4 k0 = *(const uint4*)(ksrc + (size_t)(sk0 + krow) * 3072 + kch * 8);
    uint4 k1 = *(const uint4*)(ksrc + (size_t)(sk0 + 32 + krow) * 3072 + kch * 8);
    uint4 v0 = *(const uint4*)(vsrc + (size_t)vrow * 4096 + sk0 + vch * 8);
    uint4 v1 = *(const uint4*)(vsrc + (size_t)(64 + vrow) * 4096 + sk0 + vch * 8);

    __syncthreads();  // all waves done reading Ks/Vs of tile kt-1
    *(uint4*)&Ks[krow * 136 + kch * 8] = k0;
    *(uint4*)&Ks[(32 + krow) * 136 + kch * 8] = k1;
    *(uint4*)&Vs[vrow * 72 + vch * 8] = v0;
    *(uint4*)&Vs[(64 + vrow) * 72 + vch * 8] = v1;
    __syncthreads();

    // ---- St = K Q^T : 16 MFMA (operands swapped; C-frag col=q, row=key) ----
    f32x4 sc[4];
    #pragma unroll
    for (int i = 0; i < 4; ++i) sc[i] = (f32x4)(0.0f);
    #pragma unroll
    for (int kk = 0; kk < 4; ++kk) {
      #pragma unroll
      for (int i = 0; i < 4; ++i) {
        bf16x8 ak = *(const bf16x8*)&Ks[(16 * i + col) * 136 + kk * 32 + quad * 8];
        sc[i] = __builtin_amdgcn_mfma_f32_16x16x32_bf16(ak, aq[kk], sc[i], 0, 0, 0);
      }
    }

    // ---- exp (max-free), mask, packed b64 P write, denominator accum ----
    if (kt * 64 + 63 > qt * 128 + w * 16) {  // wave-uniform: mask needed
      #pragma unroll
      for (int i = 0; i < 4; ++i) {
        ushort4 pk;
        float p0 = __expf(sc[i][0]);
        float p1 = __expf(sc[i][1]);
        float p2 = __expf(sc[i][2]);
        float p3 = __expf(sc[i][3]);
        const int key0 = kt * 64 + 16 * i + quad * 4;
        if (key0 + 0 > qrow) p0 = 0.0f;
        if (key0 + 1 > qrow) p1 = 0.0f;
        if (key0 + 2 > qrow) p2 = 0.0f;
        if (key0 + 3 > qrow) p3 = 0.0f;
        lsum += (p0 + p1) + (p2 + p3);
        pk.x = f2bf(p0); pk.y = f2bf(p1); pk.z = f2bf(p2); pk.w = f2bf(p3);
        *(ushort4*)&Pw[col * 72 + 16 * i + quad * 4] = pk;
      }
    } else {
      #pragma unroll
      for (int i = 0; i < 4; ++i) {
        ushort4 pk;
        float p0 = __expf(sc[i][0]);
        float p1 = __expf(sc[i][1]);
        float p2 = __expf(sc[i][2]);
        float p3 = __expf(sc[i][3]);
        lsum += (p0 + p1) + (p2 + p3);
        pk.x = f2bf(p0); pk.y = f2bf(p1); pk.z = f2bf(p2); pk.w = f2bf(p3);
        *(ushort4*)&Pw[col * 72 + 16 * i + quad * 4] = pk;
      }
    }
    // Ps is wave-private: in-wave ds ordering handles write->read

    // ---- O += P V : 16 MFMA ----
    #pragma unroll
    for (int ks = 0; ks < 2; ++ks) {
      bf16x8 ap = *(const bf16x8*)&Pw[col * 72 + ks * 32 + quad * 8];
      #pragma unroll
      for (int jd = 0; jd < 8; ++jd) {
        bf16x8 bv = *(const bf16x8*)&Vs[(16 * jd + col) * 72 + ks * 32 + quad * 8];
        o[jd] = __builtin_amdgcn_mfma_f32_16x16x32_bf16(ap, bv, o[jd], 0, 0, 0);
      }
    }
  }

  // ---- reduce denominator across quads (lanes sharing col hold q=col) ----
  lsum += __shfl_xor(lsum, 16, 64);
  lsum += __shfl_xor(lsum, 32, 64);

  // ---- normalize + store (output lands at shifted seq pos = un-shift) ----
  #pragma unroll
  for (int r = 0; r < 4; ++r) {
    const float inv = 1.0f / __shfl(lsum, quad * 4 + r, 64);
    const int qg = qt * 128 + w * 16 + quad * 4 + r;
    const int sq = (base_s + qg + shift) & 4095;
    u16* dst = Ob + ((size_t)(b * 4096 + sq)) * 2048 + h * 128;
    #pragma unroll
    for (int jd = 0; jd < 8; ++jd)
      dst[16 * jd + col] = f2bf(o[jd][r] * inv);
  }
}

// ---------------------------------------------------------------------------
extern "C" void kernel_launch(void* const* d_in, const int* in_sizes, int n_in,
                              void* d_out, int out_size, void* d_ws, size_t ws_size,
                              hipStream_t stream) {
  const float* hs = (const float*)d_in[0];
  const int*   pos = (const int*)d_in[2];
  const float* Wq = (const float*)d_in[3];
  const float* Wk = (const float*)d_in[4];
  const float* Wv = (const float*)d_in[5];
  const float* Wo = (const float*)d_in[6];

  char* ws = (char*)d_ws;
  u16* hsb   = (u16*)ws; ws += (size_t)8192 * 2048 * 2;
  u16* Wqkvt = (u16*)ws; ws += (size_t)3072 * 2048 * 2;
  u16* Wot   = (u16*)ws; ws += (size_t)2048 * 2048 * 2;
  u16* QKVb  = (u16*)ws; ws += (size_t)8192 * 3072 * 2;
  u16* Vtt   = (u16*)ws; ws += (size_t)2 * 4 * 128 * 4096 * 2;
  u16* Obh   = (u16*)ws; ws += (size_t)8192 * 2048 * 2;

  dim3 blk(256);

  cast_bf16_vec<<<16384, blk, 0, stream>>>(hs, hsb);
  // Wqkvt rows: 0..2047 = Wq^T, 2048..2559 = Wk^T, 2560..3071 = Wv^T
  wt_cast<<<dim3(32, 32), blk, 0, stream>>>(Wq, Wqkvt, 2048, 2048);
  wt_cast<<<dim3(8, 32),  blk, 0, stream>>>(Wk, Wqkvt + (size_t)2048 * 2048, 2048, 512);
  wt_cast<<<dim3(8, 32),  blk, 0, stream>>>(Wv, Wqkvt + (size_t)2560 * 2048, 2048, 512);
  wt_cast<<<dim3(32, 32), blk, 0, stream>>>(Wo, Wot, 2048, 2048);

  // Fused QKV projection: (8192 x 2048) @ (3072 x 2048)^T -> 8192 x 3072 bf16
  gemm_bf16<<<dim3(24, 64), blk, 0, stream>>>(hsb, Wqkvt, nullptr, QKVb, 8192, 3072, 2048);

  rope_qkv<<<40960, blk, 0, stream>>>(QKVb, pos);
  v_transpose<<<512, blk, 0, stream>>>(QKVb, Vtt);

  // flash attention: 1024 blocks x 512 threads
  attn_mfma<<<1024, dim3(512), 0, stream>>>(QKVb, Vtt, Obh);

  gemm_bf16<<<dim3(16, 64), blk, 0, stream>>>(Obh, Wot, (float*)d_out, nullptr, 8192, 2048, 2048);
}